// Round 10
// baseline (324.382 us; speedup 1.0000x reference)
//
#include <hip/hip_runtime.h>

using bf16 = __bf16;
typedef __bf16 bf16x2 __attribute__((ext_vector_type(2)));
typedef __bf16 bf16x4v __attribute__((ext_vector_type(4)));
typedef __bf16 bf16x8 __attribute__((ext_vector_type(8)));
typedef float f32x4 __attribute__((ext_vector_type(4)));
typedef float floatx4 __attribute__((ext_vector_type(4)));

#define MFMA16(a, b, c) __builtin_amdgcn_mfma_f32_16x16x32_bf16((a), (b), (c), 0, 0, 0)

__device__ __forceinline__ float exp2a(float x) {
  float r;
  asm("v_exp_f32 %0, %1" : "=v"(r) : "v"(x));
  return r;
}

// ---------------- cast fp32 -> bf16 (4 elems/thread) ----------------
__global__ __launch_bounds__(256) void cast_kernel(const float* __restrict__ in,
                                                   bf16* __restrict__ out, int n4) {
  int i = blockIdx.x * 256 + threadIdx.x;
  if (i >= n4) return;
  floatx4 v = *(const floatx4*)(in + (size_t)i * 4);
  bf16x4v o;
  #pragma unroll
  for (int j = 0; j < 4; ++j) o[j] = (bf16)v[j];
  *(bf16x4v*)(out + (size_t)i * 4) = o;
}

// ---------------- GEMM: C[M][N] = A[M][K] * B[N][K]^T ----------------
template <bool OUT_F32>
__global__ __launch_bounds__(256, 2) void gemm_bt(const bf16* __restrict__ A,
                                                  const bf16* __restrict__ B,
                                                  void* __restrict__ Cv,
                                                  int M, int N, int K) {
  __shared__ bf16 As[128 * 32];
  __shared__ bf16 Bs[128 * 32];
  const int t = threadIdx.x;
  const int l = t & 63;
  const int w = t >> 6;
  const int m0 = blockIdx.y * 128;
  const int n0 = blockIdx.x * 128;
  const int wr = (w >> 1) * 64;
  const int wc = (w & 1) * 64;
  const int lr = l & 15;
  const int lk = (l >> 4) * 8;

  f32x4 acc[4][4] = {};

  const int srow = t >> 2;
  const int scol = (t & 3) * 8;

  for (int k0 = 0; k0 < K; k0 += 32) {
    __syncthreads();
    #pragma unroll
    for (int j = 0; j < 2; ++j) {
      const bf16* ga = A + (size_t)(m0 + j * 64 + srow) * K + k0 + scol;
      __builtin_amdgcn_global_load_lds(
          (const __attribute__((address_space(1))) void*)ga,
          (__attribute__((address_space(3))) void*)(As + (j * 64 + srow) * 32 + scol),
          16, 0, 0);
      const bf16* gb = B + (size_t)(n0 + j * 64 + srow) * K + k0 + scol;
      __builtin_amdgcn_global_load_lds(
          (const __attribute__((address_space(1))) void*)gb,
          (__attribute__((address_space(3))) void*)(Bs + (j * 64 + srow) * 32 + scol),
          16, 0, 0);
    }
    __syncthreads();
    bf16x8 af[4], bfr[4];
    #pragma unroll
    for (int i = 0; i < 4; ++i) af[i] = *(const bf16x8*)(As + (wr + i * 16 + lr) * 32 + lk);
    #pragma unroll
    for (int i = 0; i < 4; ++i) bfr[i] = *(const bf16x8*)(Bs + (wc + i * 16 + lr) * 32 + lk);
    #pragma unroll
    for (int i = 0; i < 4; ++i)
      #pragma unroll
      for (int j = 0; j < 4; ++j)
        acc[i][j] = MFMA16(af[i], bfr[j], acc[i][j]);
  }

  const int cr0 = (l >> 4) * 4;
  const int cc = l & 15;
  #pragma unroll
  for (int i = 0; i < 4; ++i) {
    #pragma unroll
    for (int j = 0; j < 4; ++j) {
      int row = m0 + wr + i * 16 + cr0;
      int col = n0 + wc + j * 16 + cc;
      #pragma unroll
      for (int r = 0; r < 4; ++r) {
        if constexpr (OUT_F32)
          ((float*)Cv)[(size_t)(row + r) * N + col] = acc[i][j][r];
        else
          ((bf16*)Cv)[(size_t)(row + r) * N + col] = (bf16)acc[i][j][r];
      }
    }
  }
}

// ---------------- RoPE in-place on q,k of qkv [4096][3072] ----------------
__global__ __launch_bounds__(256) void rope_kernel(bf16* __restrict__ qkv,
                                                   const int* __restrict__ pos) {
  int idx = blockIdx.x * 256 + threadIdx.x;
  int i = idx & 31;
  int h = (idx >> 5) & 15;
  int row = idx >> 9;
  int s = row & 2047;
  float p = (float)pos[s];
  float freq = exp2f(-(float)i * (13.287712379549449f / 32.0f));
  float ang = p * freq;
  float sn, cs;
  sincosf(ang, &sn, &cs);
  size_t base = (size_t)row * 3072 + h * 64 + 2 * i;
  bf16x2 q = *(bf16x2*)(qkv + base);
  bf16x2 k = *(bf16x2*)(qkv + base + 1024);
  float q1 = (float)q[0], q2 = (float)q[1];
  float k1 = (float)k[0], k2 = (float)k[1];
  bf16x2 qo, ko;
  qo[0] = (bf16)(q1 * cs - q2 * sn);
  qo[1] = (bf16)(q1 * sn + q2 * cs);
  ko[0] = (bf16)(k1 * cs - k2 * sn);
  ko[1] = (bf16)(k1 * sn + k2 * cs);
  *(bf16x2*)(qkv + base) = qo;
  *(bf16x2*)(qkv + base + 1024) = ko;
}

// ---------------- causal flash attention v10: K direct global->reg ----------------
// grid: (S/64, B*H), 256 thr = 4 waves; wave w owns q rows [q0+16w, q0+16w+16).
// KV tile 64. K loaded straight into registers (8x b128 gather over 16 rows = 100%
// line-efficient, L2-resident; prefetched one tile ahead after QK). NO K LDS, no K
// barrier dependency. V dbuf in LDS (slot-permuted zero-shuffle PV). One barrier/tile.
__global__ __launch_bounds__(256, 4) void fa_causal(const bf16* __restrict__ qkv,
                                                    bf16* __restrict__ attn) {
  const int bh = blockIdx.y;
  const int b = bh >> 4, h = bh & 15;
  const int q0 = ((int)gridDim.x - 1 - (int)blockIdx.x) * 64;  // heavy blocks first
  const int t = threadIdx.x, w = t >> 6, l = t & 63;
  const int lq = l & 15;
  const int g = l >> 4;
  const int lk = g * 8;
  const int swz = lq & 7;
  const int hz = lq >> 3;

  __shared__ bf16 Vt[2][64 * 64];   // V^T dbuf, slot-permuted + XOR swizzled; epilogue reuse

  const size_t rs = 3072;
  const bf16* Qg = qkv + (size_t)(b * 2048) * rs + h * 64;
  const bf16* Kg = Qg + 1024;
  const bf16* Vg = Qg + 2048;

  const int qrow0 = q0 + w * 16;
  const int qg = qrow0 + lq;

  bf16x8 qfr[2];
  #pragma unroll
  for (int kk = 0; kk < 2; ++kk)
    qfr[kk] = *(const bf16x8*)(Qg + (size_t)qg * rs + kk * 32 + lk);

  f32x4 o[4] = {};
  float mrow = -1e30f, lrow = 0.f;
  const float SC = 0.125f * 1.44269504088896f;  // scale * log2(e)

  const int nkt = (q0 + 64) >> 6;
  const int vk = t >> 2;                 // 0..63 key row
  const int cd0 = (t & 3) * 2;           // first d-chunk of this thread
  const int vslot = (vk & 32) | (((vk >> 2) & 3) << 3) | (((vk >> 4) & 1) << 2) | (vk & 3);

  bf16x8 va, vb2;
  bf16x8 kb[4][2], kn[4][2];

  #define LOAD_K(KT, DST)                                                      \
    {                                                                          \
      _Pragma("unroll")                                                        \
      for (int kf = 0; kf < 4; ++kf)                                           \
        _Pragma("unroll")                                                      \
        for (int ks = 0; ks < 2; ++ks)                                         \
          DST[kf][ks] = *(const bf16x8*)(Kg + (size_t)((KT)*64 + kf * 16 + lq) * rs + ks * 32 + lk); \
    }
  #define LOAD_V(KT)                                                          \
    {                                                                         \
      const bf16* vsrc = Vg + (size_t)((KT)*64 + vk) * rs + cd0 * 8;          \
      va = *(const bf16x8*)(vsrc);                                            \
      vb2 = *(const bf16x8*)(vsrc + 8);                                       \
    }
  #define WRITE_V(BUF)                                                        \
    {                                                                         \
      _Pragma("unroll")                                                       \
      for (int e = 0; e < 8; ++e) {                                           \
        Vt[BUF][(cd0 * 8 + e) * 64 + (vslot ^ ((e ^ cd0) << 3))] = va[e];     \
        Vt[BUF][((cd0 + 1) * 8 + e) * 64 + (vslot ^ ((e ^ (cd0 + 1)) << 3))] = vb2[e]; \
      }                                                                       \
    }

  // ---- prologue: K(0) -> regs, V(0) -> LDS ----
  LOAD_K(0, kb)
  LOAD_V(0)
  WRITE_V(0)
  __syncthreads();

  for (int kt = 0; kt < nkt; ++kt) {
    const bool pf = (kt + 1 < nkt);
    const bool compute = (kt * 64 <= qrow0 + 15);  // wave-uniform causal skip
    const bf16* Vc = Vt[kt & 1];

    f32x4 sc[4] = {};
    if (compute) {
      __builtin_amdgcn_s_setprio(1);
      #pragma unroll
      for (int kf = 0; kf < 4; ++kf) {
        sc[kf] = MFMA16(kb[kf][0], qfr[0], sc[kf]);
        sc[kf] = MFMA16(kb[kf][1], qfr[1], sc[kf]);
      }
      __builtin_amdgcn_s_setprio(0);
    }

    // issue next tile's loads AFTER QK (kb dead now -> kn can share its registers)
    if (pf) {
      LOAD_V(kt + 1)
      LOAD_K(kt + 1, kn)
    }

    if (compute) {
      const bool fullw = (kt * 64 + 63 <= qrow0);
      float pv[16];
      float mx = -1e30f;
      if (fullw) {
        #pragma unroll
        for (int i = 0; i < 16; ++i) {
          float s = sc[i >> 2][i & 3] * SC;
          pv[i] = s;
          mx = fmaxf(mx, s);
        }
      } else {
        #pragma unroll
        for (int kf = 0; kf < 4; ++kf)
          #pragma unroll
          for (int r = 0; r < 4; ++r) {
            int key = kt * 64 + kf * 16 + g * 4 + r;
            float s = (key <= qg) ? sc[kf][r] * SC : -1e30f;
            pv[kf * 4 + r] = s;
            mx = fmaxf(mx, s);
          }
      }
      mx = fmaxf(mx, __shfl_xor(mx, 16, 64));
      mx = fmaxf(mx, __shfl_xor(mx, 32, 64));
      if (!__all(mx <= mrow)) {  // defer-max
        float mnew = fmaxf(mrow, mx);
        float al = exp2a(mrow - mnew);
        lrow *= al;
        #pragma unroll
        for (int fd = 0; fd < 4; ++fd)
          #pragma unroll
          for (int r = 0; r < 4; ++r) o[fd][r] *= al;
        mrow = mnew;
      }
      float rsum = 0.f;
      #pragma unroll
      for (int i = 0; i < 16; ++i) {
        float p = exp2a(pv[i] - mrow);
        pv[i] = p;
        rsum += p;
      }
      rsum += __shfl_xor(rsum, 16, 64);
      rsum += __shfl_xor(rsum, 32, 64);
      lrow += rsum;

      bf16x8 p0, p1;
      #pragma unroll
      for (int i = 0; i < 8; ++i) {
        p0[i] = (bf16)pv[i];
        p1[i] = (bf16)pv[8 + i];
      }

      __builtin_amdgcn_s_setprio(1);
      #pragma unroll
      for (int fd = 0; fd < 4; ++fd) {
        const int drow = fd * 16 + lq;
        {
          int pc = (0 * 4 + g) ^ swz ^ (fd << 1) ^ hz;
          bf16x8 vb = *(const bf16x8*)(&Vc[drow * 64 + pc * 8]);
          o[fd] = MFMA16(vb, p0, o[fd]);
        }
        {
          int pc = (1 * 4 + g) ^ swz ^ (fd << 1) ^ hz;
          bf16x8 vb = *(const bf16x8*)(&Vc[drow * 64 + pc * 8]);
          o[fd] = MFMA16(vb, p1, o[fd]);
        }
      }
      __builtin_amdgcn_s_setprio(0);
    }

    if (pf) {
      WRITE_V((kt + 1) & 1)  // waits V loads (K regs may still be in flight)
      __syncthreads();       // publishes V(kt+1)
      #pragma unroll
      for (int kf = 0; kf < 4; ++kf) {
        kb[kf][0] = kn[kf][0];
        kb[kf][1] = kn[kf][1];
      }
    }
  }

  // ---- epilogue: O^T -> [q][d] via LDS (reuse Vt) -> coalesced b128 stores ----
  __syncthreads();  // all waves done reading Vt
  bf16* Os = (bf16*)Vt + w * (16 * 72);
  float inv = 1.0f / lrow;
  #pragma unroll
  for (int fd = 0; fd < 4; ++fd) {
    bf16x4v ov;
    #pragma unroll
    for (int r = 0; r < 4; ++r) ov[r] = (bf16)(o[fd][r] * inv);
    *(bf16x4v*)(&Os[lq * 72 + fd * 16 + g * 4]) = ov;
  }
  asm volatile("" ::: "memory");
  #pragma unroll
  for (int p = 0; p < 2; ++p) {
    int idx = p * 64 + l;
    int row16 = idx >> 3, c8 = idx & 7;
    bf16x8 v = *(const bf16x8*)(&Os[row16 * 72 + c8 * 8]);
    *(bf16x8*)(&attn[(size_t)(b * 2048 + qrow0 + row16) * 1024 + h * 64 + c8 * 8]) = v;
  }
}

// ---------------- launch ----------------
extern "C" void kernel_launch(void* const* d_in, const int* in_sizes, int n_in,
                              void* d_out, int out_size, void* d_ws, size_t ws_size,
                              hipStream_t stream) {
  const float* x = (const float*)d_in[0];
  const int* pos = (const int*)d_in[1];
  const float* w_qkv = (const float*)d_in[2];
  const float* w_out = (const float*)d_in[3];
  float* out = (float*)d_out;

  char* ws = (char*)d_ws;
  bf16* xb   = (bf16*)(ws);
  bf16* wqb  = (bf16*)(ws + (8u << 20));
  bf16* wob  = (bf16*)(ws + (14u << 20));
  bf16* qkv  = (bf16*)(ws + (16u << 20));
  bf16* attn = (bf16*)(ws + (40u << 20));

  cast_kernel<<<4096, 256, 0, stream>>>(x, xb, 4194304 / 4);
  cast_kernel<<<3072, 256, 0, stream>>>(w_qkv, wqb, 3145728 / 4);
  cast_kernel<<<1024, 256, 0, stream>>>(w_out, wob, 1048576 / 4);

  dim3 g1(3072 / 128, 4096 / 128);
  gemm_bt<false><<<g1, 256, 0, stream>>>(xb, wqb, (void*)qkv, 4096, 3072, 1024);

  rope_kernel<<<8192, 256, 0, stream>>>(qkv, pos);

  dim3 gfa(2048 / 64, 32);
  fa_causal<<<gfa, 256, 0, stream>>>(qkv, attn);

  dim3 g2(1024 / 128, 4096 / 128);
  gemm_bt<true><<<g2, 256, 0, stream>>>(attn, wob, (void*)out, 4096, 1024, 1024);
}

// Round 11
// 124.548 us; speedup vs baseline: 2.6045x; 2.6045x over previous
//
#include <hip/hip_runtime.h>

using bf16 = __bf16;
typedef __bf16 bf16x2 __attribute__((ext_vector_type(2)));
typedef __bf16 bf16x4v __attribute__((ext_vector_type(4)));
typedef __bf16 bf16x8 __attribute__((ext_vector_type(8)));
typedef float f32x4 __attribute__((ext_vector_type(4)));
typedef float floatx4 __attribute__((ext_vector_type(4)));

#define MFMA16(a, b, c) __builtin_amdgcn_mfma_f32_16x16x32_bf16((a), (b), (c), 0, 0, 0)

__device__ __forceinline__ float exp2a(float x) {
  float r;
  asm("v_exp_f32 %0, %1" : "=v"(r) : "v"(x));
  return r;
}

// ---------------- cast fp32 -> bf16 (4 elems/thread) ----------------
__global__ __launch_bounds__(256) void cast_kernel(const float* __restrict__ in,
                                                   bf16* __restrict__ out, int n4) {
  int i = blockIdx.x * 256 + threadIdx.x;
  if (i >= n4) return;
  floatx4 v = *(const floatx4*)(in + (size_t)i * 4);
  bf16x4v o;
  #pragma unroll
  for (int j = 0; j < 4; ++j) o[j] = (bf16)v[j];
  *(bf16x4v*)(out + (size_t)i * 4) = o;
}

// ---------------- GEMM: C[M][N] = A[M][K] * B[N][K]^T ----------------
template <bool OUT_F32>
__global__ __launch_bounds__(256, 2) void gemm_bt(const bf16* __restrict__ A,
                                                  const bf16* __restrict__ B,
                                                  void* __restrict__ Cv,
                                                  int M, int N, int K) {
  __shared__ bf16 As[128 * 32];
  __shared__ bf16 Bs[128 * 32];
  const int t = threadIdx.x;
  const int l = t & 63;
  const int w = t >> 6;
  const int m0 = blockIdx.y * 128;
  const int n0 = blockIdx.x * 128;
  const int wr = (w >> 1) * 64;
  const int wc = (w & 1) * 64;
  const int lr = l & 15;
  const int lk = (l >> 4) * 8;

  f32x4 acc[4][4] = {};

  const int srow = t >> 2;
  const int scol = (t & 3) * 8;

  for (int k0 = 0; k0 < K; k0 += 32) {
    __syncthreads();
    #pragma unroll
    for (int j = 0; j < 2; ++j) {
      const bf16* ga = A + (size_t)(m0 + j * 64 + srow) * K + k0 + scol;
      __builtin_amdgcn_global_load_lds(
          (const __attribute__((address_space(1))) void*)ga,
          (__attribute__((address_space(3))) void*)(As + (j * 64 + srow) * 32 + scol),
          16, 0, 0);
      const bf16* gb = B + (size_t)(n0 + j * 64 + srow) * K + k0 + scol;
      __builtin_amdgcn_global_load_lds(
          (const __attribute__((address_space(1))) void*)gb,
          (__attribute__((address_space(3))) void*)(Bs + (j * 64 + srow) * 32 + scol),
          16, 0, 0);
    }
    __syncthreads();
    bf16x8 af[4], bfr[4];
    #pragma unroll
    for (int i = 0; i < 4; ++i) af[i] = *(const bf16x8*)(As + (wr + i * 16 + lr) * 32 + lk);
    #pragma unroll
    for (int i = 0; i < 4; ++i) bfr[i] = *(const bf16x8*)(Bs + (wc + i * 16 + lr) * 32 + lk);
    #pragma unroll
    for (int i = 0; i < 4; ++i)
      #pragma unroll
      for (int j = 0; j < 4; ++j)
        acc[i][j] = MFMA16(af[i], bfr[j], acc[i][j]);
  }

  const int cr0 = (l >> 4) * 4;
  const int cc = l & 15;
  #pragma unroll
  for (int i = 0; i < 4; ++i) {
    #pragma unroll
    for (int j = 0; j < 4; ++j) {
      int row = m0 + wr + i * 16 + cr0;
      int col = n0 + wc + j * 16 + cc;
      #pragma unroll
      for (int r = 0; r < 4; ++r) {
        if constexpr (OUT_F32)
          ((float*)Cv)[(size_t)(row + r) * N + col] = acc[i][j][r];
        else
          ((bf16*)Cv)[(size_t)(row + r) * N + col] = (bf16)acc[i][j][r];
      }
    }
  }
}

// ---------------- RoPE in-place on q,k of qkv [4096][3072] ----------------
__global__ __launch_bounds__(256) void rope_kernel(bf16* __restrict__ qkv,
                                                   const int* __restrict__ pos) {
  int idx = blockIdx.x * 256 + threadIdx.x;
  int i = idx & 31;
  int h = (idx >> 5) & 15;
  int row = idx >> 9;
  int s = row & 2047;
  float p = (float)pos[s];
  float freq = exp2f(-(float)i * (13.287712379549449f / 32.0f));
  float ang = p * freq;
  float sn, cs;
  sincosf(ang, &sn, &cs);
  size_t base = (size_t)row * 3072 + h * 64 + 2 * i;
  bf16x2 q = *(bf16x2*)(qkv + base);
  bf16x2 k = *(bf16x2*)(qkv + base + 1024);
  float q1 = (float)q[0], q2 = (float)q[1];
  float k1 = (float)k[0], k2 = (float)k[1];
  bf16x2 qo, ko;
  qo[0] = (bf16)(q1 * cs - q2 * sn);
  qo[1] = (bf16)(q1 * sn + q2 * cs);
  ko[0] = (bf16)(k1 * cs - k2 * sn);
  ko[1] = (bf16)(k1 * sn + k2 * cs);
  *(bf16x2*)(qkv + base) = qo;
  *(bf16x2*)(qkv + base + 1024) = ko;
}

// ---------------- causal flash attention v11: v8 + issue-slot cuts + L2 pinning -------
// grid: (B*H, S/64): x = bh (XCD = bh%8 -> K/V L2-pinned per XCD), y = q-tile reversed.
// 256 thr = 4 waves; wave w owns q rows [q0+16w, q0+16w+16). KV tile 64, K+V dbuf.
// SC folded into Q regs; lane-local defer-max check; V staged as key-pairs (b32 writes).
__global__ __launch_bounds__(256, 4) void fa_causal(const bf16* __restrict__ qkv,
                                                    bf16* __restrict__ attn) {
  const int bh = blockIdx.x;
  const int b = bh >> 4, h = bh & 15;
  const int q0 = ((int)gridDim.y - 1 - (int)blockIdx.y) * 64;  // heavy blocks first
  const int t = threadIdx.x, w = t >> 6, l = t & 63;
  const int lq = l & 15;
  const int g = l >> 4;
  const int lk = g * 8;
  const int swz = lq & 7;
  const int hz = lq >> 3;

  __shared__ bf16 Ks[2][64 * 64];   // K dbuf, source-XOR swizzled; epilogue reuse
  __shared__ bf16 Vt[2][64 * 64];   // V^T dbuf, slot-permuted + XOR swizzled

  const size_t rs = 3072;
  const bf16* Qg = qkv + (size_t)(b * 2048) * rs + h * 64;
  const bf16* Kg = Qg + 1024;
  const bf16* Vg = Qg + 2048;

  const int qrow0 = q0 + w * 16;
  const int qg = qrow0 + lq;

  const float SC = 0.125f * 1.44269504088896f;  // scale * log2(e), folded into Q
  bf16x8 qfr[2];
  #pragma unroll
  for (int kk = 0; kk < 2; ++kk) {
    bf16x8 qv = *(const bf16x8*)(Qg + (size_t)qg * rs + kk * 32 + lk);
    #pragma unroll
    for (int j = 0; j < 8; ++j) qv[j] = (bf16)((float)qv[j] * SC);
    qfr[kk] = qv;
  }

  f32x4 o[4] = {};
  float mrow = -1e30f, lrow = 0.f;

  const int nkt = (q0 + 64) >> 6;
  const int krow_in = l >> 3;            // 0..7
  const int kcsrc = (l & 7) ^ krow_in;   // pre-swizzled source chunk
  const int kp = t >> 3;                 // 0..31 key pair
  const int K0 = kp * 2;
  const int cd = t & 7;                  // d chunk 0..7
  // slot permutation (bijective); slot(K0+1) = slot(K0)|1
  const int slot0 = (K0 & 32) | (((K0 >> 2) & 3) << 3) | (((K0 >> 4) & 1) << 2) | (K0 & 3);

  bf16x8 va, vb2;

  #define STAGE_K(KT, BUF)                                                                \
    {                                                                                     \
      _Pragma("unroll")                                                                   \
      for (int c = 0; c < 2; ++c) {                                                       \
        const int rowbase = w * 8 + c * 32;                                               \
        const bf16* src = Kg + (size_t)((KT)*64 + rowbase + krow_in) * rs + kcsrc * 8;    \
        __builtin_amdgcn_global_load_lds(                                                 \
            (const __attribute__((address_space(1))) void*)src,                           \
            (__attribute__((address_space(3))) void*)(&Ks[BUF][rowbase * 64]), 16, 0, 0); \
      }                                                                                   \
    }
  #define LOAD_V(KT)                                                          \
    {                                                                         \
      const bf16* vsrc = Vg + (size_t)((KT)*64 + K0) * rs + cd * 8;           \
      va = *(const bf16x8*)(vsrc);                                            \
      vb2 = *(const bf16x8*)(vsrc + rs);                                      \
    }
  #define WRITE_V(BUF)                                                        \
    {                                                                         \
      _Pragma("unroll")                                                       \
      for (int e = 0; e < 8; ++e) {                                           \
        bf16x2 pr;                                                            \
        pr[0] = va[e];                                                        \
        pr[1] = vb2[e];                                                       \
        *(bf16x2*)(&Vt[BUF][(cd * 8 + e) * 64 + (slot0 ^ ((e ^ cd) << 3))]) = pr; \
      }                                                                       \
    }

  STAGE_K(0, 0)
  LOAD_V(0)
  WRITE_V(0)
  __syncthreads();

  for (int kt = 0; kt < nkt; ++kt) {
    const bool pf = (kt + 1 < nkt);
    if (pf) {
      LOAD_V(kt + 1)
      STAGE_K(kt + 1, (kt + 1) & 1)
    }

    if (kt * 64 <= qrow0 + 15) {  // wave-uniform causal skip
      const bf16* Kc = Ks[kt & 1];
      const bf16* Vc = Vt[kt & 1];
      const bool fullw = (kt * 64 + 63 <= qrow0);

      f32x4 sc[4] = {};
      __builtin_amdgcn_s_setprio(1);
      #pragma unroll
      for (int kf = 0; kf < 4; ++kf) {
        const int krow = kf * 16 + lq;
        bf16x8 kb0 = *(const bf16x8*)(&Kc[krow * 64 + ((0 + g) ^ swz) * 8]);
        bf16x8 kb1 = *(const bf16x8*)(&Kc[krow * 64 + ((4 + g) ^ swz) * 8]);
        sc[kf] = MFMA16(kb0, qfr[0], sc[kf]);
        sc[kf] = MFMA16(kb1, qfr[1], sc[kf]);
      }
      __builtin_amdgcn_s_setprio(0);

      float pv[16];
      if (fullw) {
        #pragma unroll
        for (int i = 0; i < 16; ++i) pv[i] = sc[i >> 2][i & 3];
      } else {
        #pragma unroll
        for (int kf = 0; kf < 4; ++kf)
          #pragma unroll
          for (int r = 0; r < 4; ++r) {
            int key = kt * 64 + kf * 16 + g * 4 + r;
            pv[kf * 4 + r] = (key <= qg) ? sc[kf][r] : -1e30f;
          }
      }
      // max3-shaped lane-local max (8 ops with v_max3 fusion)
      float mxl = fmaxf(fmaxf(pv[0], pv[1]), pv[2]);
      mxl = fmaxf(fmaxf(mxl, pv[3]), pv[4]);
      mxl = fmaxf(fmaxf(mxl, pv[5]), pv[6]);
      mxl = fmaxf(fmaxf(mxl, pv[7]), pv[8]);
      mxl = fmaxf(fmaxf(mxl, pv[9]), pv[10]);
      mxl = fmaxf(fmaxf(mxl, pv[11]), pv[12]);
      mxl = fmaxf(fmaxf(mxl, pv[13]), pv[14]);
      mxl = fmaxf(mxl, pv[15]);
      // lane-local defer-max check: shfl-reduce only when some row max grew
      if (!__all(mxl <= mrow)) {
        float mx = fmaxf(mxl, __shfl_xor(mxl, 16, 64));
        mx = fmaxf(mx, __shfl_xor(mx, 32, 64));
        float mnew = fmaxf(mrow, mx);
        float al = exp2a(mrow - mnew);
        lrow *= al;
        #pragma unroll
        for (int fd = 0; fd < 4; ++fd)
          #pragma unroll
          for (int r = 0; r < 4; ++r) o[fd][r] *= al;
        mrow = mnew;
      }
      float rsum = 0.f;
      #pragma unroll
      for (int i = 0; i < 16; ++i) {
        float p = exp2a(pv[i] - mrow);
        pv[i] = p;
        rsum += p;
      }
      rsum += __shfl_xor(rsum, 16, 64);
      rsum += __shfl_xor(rsum, 32, 64);
      lrow += rsum;

      // zero-shuffle B-frags (slot permutation absorbs the relayout)
      bf16x8 p0, p1;
      #pragma unroll
      for (int i = 0; i < 8; ++i) {
        p0[i] = (bf16)pv[i];
        p1[i] = (bf16)pv[8 + i];
      }

      __builtin_amdgcn_s_setprio(1);
      #pragma unroll
      for (int fd = 0; fd < 4; ++fd) {
        const int drow = fd * 16 + lq;
        {
          int pc = (0 * 4 + g) ^ swz ^ (fd << 1) ^ hz;
          bf16x8 vb = *(const bf16x8*)(&Vc[drow * 64 + pc * 8]);
          o[fd] = MFMA16(vb, p0, o[fd]);
        }
        {
          int pc = (1 * 4 + g) ^ swz ^ (fd << 1) ^ hz;
          bf16x8 vb = *(const bf16x8*)(&Vc[drow * 64 + pc * 8]);
          o[fd] = MFMA16(vb, p1, o[fd]);
        }
      }
      __builtin_amdgcn_s_setprio(0);
    }

    if (pf) {
      WRITE_V((kt + 1) & 1)  // other buffer: safe before barrier
      __syncthreads();       // publishes V stores + K gll for tile kt+1
    }
  }

  // ---- epilogue: O^T -> [q][d] via LDS (reuse Ks) -> coalesced b128 stores ----
  __syncthreads();  // all waves done reading K/V
  bf16* Os = (bf16*)Ks + w * (16 * 72);
  float inv = 1.0f / lrow;
  #pragma unroll
  for (int fd = 0; fd < 4; ++fd) {
    bf16x4v ov;
    #pragma unroll
    for (int r = 0; r < 4; ++r) ov[r] = (bf16)(o[fd][r] * inv);
    *(bf16x4v*)(&Os[lq * 72 + fd * 16 + g * 4]) = ov;
  }
  asm volatile("" ::: "memory");
  #pragma unroll
  for (int p = 0; p < 2; ++p) {
    int idx = p * 64 + l;
    int row16 = idx >> 3, c8 = idx & 7;
    bf16x8 v = *(const bf16x8*)(&Os[row16 * 72 + c8 * 8]);
    *(bf16x8*)(&attn[(size_t)(b * 2048 + qrow0 + row16) * 1024 + h * 64 + c8 * 8]) = v;
  }
}

// ---------------- launch ----------------
extern "C" void kernel_launch(void* const* d_in, const int* in_sizes, int n_in,
                              void* d_out, int out_size, void* d_ws, size_t ws_size,
                              hipStream_t stream) {
  const float* x = (const float*)d_in[0];
  const int* pos = (const int*)d_in[1];
  const float* w_qkv = (const float*)d_in[2];
  const float* w_out = (const float*)d_in[3];
  float* out = (float*)d_out;

  char* ws = (char*)d_ws;
  bf16* xb   = (bf16*)(ws);
  bf16* wqb  = (bf16*)(ws + (8u << 20));
  bf16* wob  = (bf16*)(ws + (14u << 20));
  bf16* qkv  = (bf16*)(ws + (16u << 20));
  bf16* attn = (bf16*)(ws + (40u << 20));

  cast_kernel<<<4096, 256, 0, stream>>>(x, xb, 4194304 / 4);
  cast_kernel<<<3072, 256, 0, stream>>>(w_qkv, wqb, 3145728 / 4);
  cast_kernel<<<1024, 256, 0, stream>>>(w_out, wob, 1048576 / 4);

  dim3 g1(3072 / 128, 4096 / 128);
  gemm_bt<false><<<g1, 256, 0, stream>>>(xb, wqb, (void*)qkv, 4096, 3072, 1024);

  rope_kernel<<<8192, 256, 0, stream>>>(qkv, pos);

  dim3 gfa(32, 2048 / 64);  // x = bh (XCD pin), y = q-tile (reversed in kernel)
  fa_causal<<<gfa, 256, 0, stream>>>(qkv, attn);

  dim3 g2(1024 / 128, 4096 / 128);
  gemm_bt<true><<<g2, 256, 0, stream>>>(attn, wob, (void*)out, 4096, 1024, 1024);
}

// Round 12
// 114.630 us; speedup vs baseline: 2.8298x; 1.0865x over previous
//
#include <hip/hip_runtime.h>

using bf16 = __bf16;
typedef __bf16 bf16x2 __attribute__((ext_vector_type(2)));
typedef __bf16 bf16x4v __attribute__((ext_vector_type(4)));
typedef __bf16 bf16x8 __attribute__((ext_vector_type(8)));
typedef float f32x4 __attribute__((ext_vector_type(4)));
typedef float floatx4 __attribute__((ext_vector_type(4)));

#define MFMA16(a, b, c) __builtin_amdgcn_mfma_f32_16x16x32_bf16((a), (b), (c), 0, 0, 0)

__device__ __forceinline__ float exp2a(float x) {
  float r;
  asm("v_exp_f32 %0, %1" : "=v"(r) : "v"(x));
  return r;
}

// ---------------- fused cast fp32 -> bf16 for x, w_qkv, w_out (one launch) ----------------
__global__ __launch_bounds__(256) void cast3_kernel(const float* __restrict__ a,
                                                    const float* __restrict__ b,
                                                    const float* __restrict__ c,
                                                    bf16* __restrict__ oa,
                                                    bf16* __restrict__ ob,
                                                    bf16* __restrict__ oc) {
  int i = blockIdx.x * 256 + threadIdx.x;  // [0, 2097152)
  const float* in;
  bf16* out;
  int off;
  if (i < 1048576) {               // x: 4M elems
    in = a; out = oa; off = i;
  } else if (i < 1835008) {        // w_qkv: 3M elems
    in = b; out = ob; off = i - 1048576;
  } else {                         // w_out: 1M elems
    in = c; out = oc; off = i - 1835008;
  }
  floatx4 v = *(const floatx4*)(in + (size_t)off * 4);
  bf16x4v o;
  #pragma unroll
  for (int j = 0; j < 4; ++j) o[j] = (bf16)v[j];
  *(bf16x4v*)(out + (size_t)off * 4) = o;
}

// ---------------- GEMM: C[M][N] = A[M][K] * B[N][K]^T (+ optional fused RoPE) ----------
// ROPE: applied to output cols < 2048 (q,k) -- block-uniform since n0 % 128 == 0.
// Pair partner col^1 lives in lane cc^1 (shfl_xor 1). Trig: v_sin/v_cos (revolutions).
template <bool OUT_F32, bool ROPE>
__global__ __launch_bounds__(256, 2) void gemm_bt(const bf16* __restrict__ A,
                                                  const bf16* __restrict__ B,
                                                  void* __restrict__ Cv,
                                                  int M, int N, int K,
                                                  const int* __restrict__ pos) {
  __shared__ bf16 As[128 * 32];
  __shared__ bf16 Bs[128 * 32];
  const int t = threadIdx.x;
  const int l = t & 63;
  const int w = t >> 6;
  const int m0 = blockIdx.y * 128;
  const int n0 = blockIdx.x * 128;
  const int wr = (w >> 1) * 64;
  const int wc = (w & 1) * 64;
  const int lr = l & 15;
  const int lk = (l >> 4) * 8;

  f32x4 acc[4][4] = {};

  const int srow = t >> 2;
  const int scol = (t & 3) * 8;

  for (int k0 = 0; k0 < K; k0 += 32) {
    __syncthreads();
    #pragma unroll
    for (int j = 0; j < 2; ++j) {
      const bf16* ga = A + (size_t)(m0 + j * 64 + srow) * K + k0 + scol;
      __builtin_amdgcn_global_load_lds(
          (const __attribute__((address_space(1))) void*)ga,
          (__attribute__((address_space(3))) void*)(As + (j * 64 + srow) * 32 + scol),
          16, 0, 0);
      const bf16* gb = B + (size_t)(n0 + j * 64 + srow) * K + k0 + scol;
      __builtin_amdgcn_global_load_lds(
          (const __attribute__((address_space(1))) void*)gb,
          (__attribute__((address_space(3))) void*)(Bs + (j * 64 + srow) * 32 + scol),
          16, 0, 0);
    }
    __syncthreads();
    bf16x8 af[4], bfr[4];
    #pragma unroll
    for (int i = 0; i < 4; ++i) af[i] = *(const bf16x8*)(As + (wr + i * 16 + lr) * 32 + lk);
    #pragma unroll
    for (int i = 0; i < 4; ++i) bfr[i] = *(const bf16x8*)(Bs + (wc + i * 16 + lr) * 32 + lk);
    #pragma unroll
    for (int i = 0; i < 4; ++i)
      #pragma unroll
      for (int j = 0; j < 4; ++j)
        acc[i][j] = MFMA16(af[i], bfr[j], acc[i][j]);
  }

  const int cr0 = (l >> 4) * 4;
  const int cc = l & 15;

  if constexpr (ROPE) {
    if (n0 < 2048) {  // q or k block (block-uniform)
      const float L2T32 = 13.287712379549449f / 32.0f;     // log2(theta)/32
      const float INV2PI = 0.15915494309189535f;
      float frev[4];
      #pragma unroll
      for (int j = 0; j < 4; ++j) {
        int col = n0 + wc + j * 16 + cc;
        int ip = (col & 63) >> 1;
        frev[j] = exp2f(-(float)ip * L2T32) * INV2PI;      // freq / 2pi
      }
      const float sgn = (cc & 1) ? 1.f : -1.f;
      #pragma unroll
      for (int i = 0; i < 4; ++i) {
        #pragma unroll
        for (int r = 0; r < 4; ++r) {
          int row = m0 + wr + i * 16 + cr0 + r;
          float p = (float)pos[row & 2047];
          #pragma unroll
          for (int j = 0; j < 4; ++j) {
            float self = acc[i][j][r];
            float partner = __shfl_xor(self, 1, 64);
            float ang = p * frev[j];
            float fr = ang - floorf(ang);
            float sn, cs;
            asm("v_sin_f32 %0, %1" : "=v"(sn) : "v"(fr));  // sin(2*pi*fr)
            asm("v_cos_f32 %0, %1" : "=v"(cs) : "v"(fr));
            acc[i][j][r] = self * cs + sgn * sn * partner;
          }
        }
      }
    }
  }

  #pragma unroll
  for (int i = 0; i < 4; ++i) {
    #pragma unroll
    for (int j = 0; j < 4; ++j) {
      int row = m0 + wr + i * 16 + cr0;
      int col = n0 + wc + j * 16 + cc;
      #pragma unroll
      for (int r = 0; r < 4; ++r) {
        if constexpr (OUT_F32)
          ((float*)Cv)[(size_t)(row + r) * N + col] = acc[i][j][r];
        else
          ((bf16*)Cv)[(size_t)(row + r) * N + col] = (bf16)acc[i][j][r];
      }
    }
  }
}

// ---------------- causal flash attention v11 (unchanged from round 11) ----------------
__global__ __launch_bounds__(256, 4) void fa_causal(const bf16* __restrict__ qkv,
                                                    bf16* __restrict__ attn) {
  const int bh = blockIdx.x;
  const int b = bh >> 4, h = bh & 15;
  const int q0 = ((int)gridDim.y - 1 - (int)blockIdx.y) * 64;  // heavy blocks first
  const int t = threadIdx.x, w = t >> 6, l = t & 63;
  const int lq = l & 15;
  const int g = l >> 4;
  const int lk = g * 8;
  const int swz = lq & 7;
  const int hz = lq >> 3;

  __shared__ bf16 Ks[2][64 * 64];   // K dbuf, source-XOR swizzled; epilogue reuse
  __shared__ bf16 Vt[2][64 * 64];   // V^T dbuf, slot-permuted + XOR swizzled

  const size_t rs = 3072;
  const bf16* Qg = qkv + (size_t)(b * 2048) * rs + h * 64;
  const bf16* Kg = Qg + 1024;
  const bf16* Vg = Qg + 2048;

  const int qrow0 = q0 + w * 16;
  const int qg = qrow0 + lq;

  const float SC = 0.125f * 1.44269504088896f;  // scale * log2(e), folded into Q
  bf16x8 qfr[2];
  #pragma unroll
  for (int kk = 0; kk < 2; ++kk) {
    bf16x8 qv = *(const bf16x8*)(Qg + (size_t)qg * rs + kk * 32 + lk);
    #pragma unroll
    for (int j = 0; j < 8; ++j) qv[j] = (bf16)((float)qv[j] * SC);
    qfr[kk] = qv;
  }

  f32x4 o[4] = {};
  float mrow = -1e30f, lrow = 0.f;

  const int nkt = (q0 + 64) >> 6;
  const int krow_in = l >> 3;            // 0..7
  const int kcsrc = (l & 7) ^ krow_in;   // pre-swizzled source chunk
  const int kp = t >> 3;                 // 0..31 key pair
  const int K0 = kp * 2;
  const int cd = t & 7;                  // d chunk 0..7
  const int slot0 = (K0 & 32) | (((K0 >> 2) & 3) << 3) | (((K0 >> 4) & 1) << 2) | (K0 & 3);

  bf16x8 va, vb2;

  #define STAGE_K(KT, BUF)                                                                \
    {                                                                                     \
      _Pragma("unroll")                                                                   \
      for (int c = 0; c < 2; ++c) {                                                       \
        const int rowbase = w * 8 + c * 32;                                               \
        const bf16* src = Kg + (size_t)((KT)*64 + rowbase + krow_in) * rs + kcsrc * 8;    \
        __builtin_amdgcn_global_load_lds(                                                 \
            (const __attribute__((address_space(1))) void*)src,                           \
            (__attribute__((address_space(3))) void*)(&Ks[BUF][rowbase * 64]), 16, 0, 0); \
      }                                                                                   \
    }
  #define LOAD_V(KT)                                                          \
    {                                                                         \
      const bf16* vsrc = Vg + (size_t)((KT)*64 + K0) * rs + cd * 8;           \
      va = *(const bf16x8*)(vsrc);                                            \
      vb2 = *(const bf16x8*)(vsrc + rs);                                      \
    }
  #define WRITE_V(BUF)                                                        \
    {                                                                         \
      _Pragma("unroll")                                                       \
      for (int e = 0; e < 8; ++e) {                                           \
        bf16x2 pr;                                                            \
        pr[0] = va[e];                                                        \
        pr[1] = vb2[e];                                                       \
        *(bf16x2*)(&Vt[BUF][(cd * 8 + e) * 64 + (slot0 ^ ((e ^ cd) << 3))]) = pr; \
      }                                                                       \
    }

  STAGE_K(0, 0)
  LOAD_V(0)
  WRITE_V(0)
  __syncthreads();

  for (int kt = 0; kt < nkt; ++kt) {
    const bool pf = (kt + 1 < nkt);
    if (pf) {
      LOAD_V(kt + 1)
      STAGE_K(kt + 1, (kt + 1) & 1)
    }

    if (kt * 64 <= qrow0 + 15) {  // wave-uniform causal skip
      const bf16* Kc = Ks[kt & 1];
      const bf16* Vc = Vt[kt & 1];
      const bool fullw = (kt * 64 + 63 <= qrow0);

      f32x4 sc[4] = {};
      __builtin_amdgcn_s_setprio(1);
      #pragma unroll
      for (int kf = 0; kf < 4; ++kf) {
        const int krow = kf * 16 + lq;
        bf16x8 kb0 = *(const bf16x8*)(&Kc[krow * 64 + ((0 + g) ^ swz) * 8]);
        bf16x8 kb1 = *(const bf16x8*)(&Kc[krow * 64 + ((4 + g) ^ swz) * 8]);
        sc[kf] = MFMA16(kb0, qfr[0], sc[kf]);
        sc[kf] = MFMA16(kb1, qfr[1], sc[kf]);
      }
      __builtin_amdgcn_s_setprio(0);

      float pv[16];
      if (fullw) {
        #pragma unroll
        for (int i = 0; i < 16; ++i) pv[i] = sc[i >> 2][i & 3];
      } else {
        #pragma unroll
        for (int kf = 0; kf < 4; ++kf)
          #pragma unroll
          for (int r = 0; r < 4; ++r) {
            int key = kt * 64 + kf * 16 + g * 4 + r;
            pv[kf * 4 + r] = (key <= qg) ? sc[kf][r] : -1e30f;
          }
      }
      float mxl = fmaxf(fmaxf(pv[0], pv[1]), pv[2]);
      mxl = fmaxf(fmaxf(mxl, pv[3]), pv[4]);
      mxl = fmaxf(fmaxf(mxl, pv[5]), pv[6]);
      mxl = fmaxf(fmaxf(mxl, pv[7]), pv[8]);
      mxl = fmaxf(fmaxf(mxl, pv[9]), pv[10]);
      mxl = fmaxf(fmaxf(mxl, pv[11]), pv[12]);
      mxl = fmaxf(fmaxf(mxl, pv[13]), pv[14]);
      mxl = fmaxf(mxl, pv[15]);
      if (!__all(mxl <= mrow)) {
        float mx = fmaxf(mxl, __shfl_xor(mxl, 16, 64));
        mx = fmaxf(mx, __shfl_xor(mx, 32, 64));
        float mnew = fmaxf(mrow, mx);
        float al = exp2a(mrow - mnew);
        lrow *= al;
        #pragma unroll
        for (int fd = 0; fd < 4; ++fd)
          #pragma unroll
          for (int r = 0; r < 4; ++r) o[fd][r] *= al;
        mrow = mnew;
      }
      float rsum = 0.f;
      #pragma unroll
      for (int i = 0; i < 16; ++i) {
        float p = exp2a(pv[i] - mrow);
        pv[i] = p;
        rsum += p;
      }
      rsum += __shfl_xor(rsum, 16, 64);
      rsum += __shfl_xor(rsum, 32, 64);
      lrow += rsum;

      bf16x8 p0, p1;
      #pragma unroll
      for (int i = 0; i < 8; ++i) {
        p0[i] = (bf16)pv[i];
        p1[i] = (bf16)pv[8 + i];
      }

      __builtin_amdgcn_s_setprio(1);
      #pragma unroll
      for (int fd = 0; fd < 4; ++fd) {
        const int drow = fd * 16 + lq;
        {
          int pc = (0 * 4 + g) ^ swz ^ (fd << 1) ^ hz;
          bf16x8 vb = *(const bf16x8*)(&Vc[drow * 64 + pc * 8]);
          o[fd] = MFMA16(vb, p0, o[fd]);
        }
        {
          int pc = (1 * 4 + g) ^ swz ^ (fd << 1) ^ hz;
          bf16x8 vb = *(const bf16x8*)(&Vc[drow * 64 + pc * 8]);
          o[fd] = MFMA16(vb, p1, o[fd]);
        }
      }
      __builtin_amdgcn_s_setprio(0);
    }

    if (pf) {
      WRITE_V((kt + 1) & 1)
      __syncthreads();
    }
  }

  // ---- epilogue: O^T -> [q][d] via LDS (reuse Ks) -> coalesced b128 stores ----
  __syncthreads();
  bf16* Os = (bf16*)Ks + w * (16 * 72);
  float inv = 1.0f / lrow;
  #pragma unroll
  for (int fd = 0; fd < 4; ++fd) {
    bf16x4v ov;
    #pragma unroll
    for (int r = 0; r < 4; ++r) ov[r] = (bf16)(o[fd][r] * inv);
    *(bf16x4v*)(&Os[lq * 72 + fd * 16 + g * 4]) = ov;
  }
  asm volatile("" ::: "memory");
  #pragma unroll
  for (int p = 0; p < 2; ++p) {
    int idx = p * 64 + l;
    int row16 = idx >> 3, c8 = idx & 7;
    bf16x8 v = *(const bf16x8*)(&Os[row16 * 72 + c8 * 8]);
    *(bf16x8*)(&attn[(size_t)(b * 2048 + qrow0 + row16) * 1024 + h * 64 + c8 * 8]) = v;
  }
}

// ---------------- launch ----------------
extern "C" void kernel_launch(void* const* d_in, const int* in_sizes, int n_in,
                              void* d_out, int out_size, void* d_ws, size_t ws_size,
                              hipStream_t stream) {
  const float* x = (const float*)d_in[0];
  const int* pos = (const int*)d_in[1];
  const float* w_qkv = (const float*)d_in[2];
  const float* w_out = (const float*)d_in[3];
  float* out = (float*)d_out;

  char* ws = (char*)d_ws;
  bf16* xb   = (bf16*)(ws);
  bf16* wqb  = (bf16*)(ws + (8u << 20));
  bf16* wob  = (bf16*)(ws + (14u << 20));
  bf16* qkv  = (bf16*)(ws + (16u << 20));
  bf16* attn = (bf16*)(ws + (40u << 20));

  cast3_kernel<<<8192, 256, 0, stream>>>(x, w_qkv, w_out, xb, wqb, wob);

  dim3 g1(3072 / 128, 4096 / 128);
  gemm_bt<false, true><<<g1, 256, 0, stream>>>(xb, wqb, (void*)qkv, 4096, 3072, 1024, pos);

  dim3 gfa(32, 2048 / 64);  // x = bh (XCD pin), y = q-tile (reversed in kernel)
  fa_causal<<<gfa, 256, 0, stream>>>(qkv, attn);

  dim3 g2(1024 / 128, 4096 / 128);
  gemm_bt<true, false><<<g2, 256, 0, stream>>>(attn, wob, (void*)out, 4096, 1024, 1024, nullptr);
}